// Round 3
// baseline (122.062 us; speedup 1.0000x reference)
//
#include <hip/hip_runtime.h>

#define NPTS 1024
#define NA   60
#define CIN  64
#define KSZ  3
#define ANN  8
#define COUT 128
#define KD   192   // i' = k_s*64 + c, 6 k-tiles of 32

using bf16x8 = __attribute__((ext_vector_type(8))) short;
using f32x4  = __attribute__((ext_vector_type(4))) float;

__device__ __forceinline__ unsigned short f2bf(float f) {
    unsigned int u = __builtin_bit_cast(unsigned int, f);
    u += 0x7FFFu + ((u >> 16) & 1u);          // RNE
    return (unsigned short)(u >> 16);
}

// ---------------- pre-kernel: build W_frag + S_frag in d_ws ----------------
// ws[0 .. 24576)        : W_frag[mt=8][kt=6][lane=64][j=8]  bf16, A-frag layout,
//                         value = W[mt*16+(l&15)][ i=c*3+ks ] with i' = kt*32+8g+j = ks*64+c
// ws[24576 .. 36864)    : S_frag[nt=12][kt=2][lane=64][j=8] bf16, B-frag layout,
//                         value = S[a' = kt*32+8g+j][ n' = nt*16+(l&15) ],
//                         S[a'][ks*60+o] = sum_a w[o,ks,a]*[idx[o,ks,a]==a'], zero-padded
__global__ void build_tables(const float* __restrict__ intra_w,
                             const float* __restrict__ W,
                             const int*   __restrict__ intra_idx,
                             unsigned short* __restrict__ ws) {
    int f = blockIdx.x * 256 + threadIdx.x;
    if (f < 24576) {
        int j = f & 7, l = (f >> 3) & 63, x = f >> 9;
        int kt = x % 6, mt = x / 6;
        int m  = mt * 16 + (l & 15);
        int ip = kt * 32 + 8 * (l >> 4) + j;      // i'
        int c  = ip & 63, ks = ip >> 6;
        ws[f] = f2bf(W[m * KD + c * KSZ + ks]);
    } else if (f < 36864) {
        int f2 = f - 24576;
        int j = f2 & 7, l = (f2 >> 3) & 63;
        int kt = (f2 >> 9) & 1, nt = f2 >> 10;
        int np = nt * 16 + (l & 15);              // n' = ks*60+o
        int ap = kt * 32 + 8 * (l >> 4) + j;      // a'
        float s = 0.f;
        if (np < 180 && ap < 60) {
            int ks = (np >= 120) ? 2 : ((np >= 60) ? 1 : 0);
            int o  = np - 60 * ks;
            const int*   ix = intra_idx + (o * KSZ + ks) * ANN;
            const float* wx = intra_w   + (o * KSZ + ks) * ANN;
            #pragma unroll
            for (int a = 0; a < ANN; a++) s += (ix[a] == ap) ? wx[a] : 0.f;
        }
        ws[f] = f2bf(s);
    }
}

// ---------------- main kernel: one block per (b,p), 256 threads ----------------
__global__ __launch_bounds__(256, 4)
void intrazp_mfma(const float* __restrict__ feats,
                  const float* __restrict__ bias,
                  const unsigned short* __restrict__ ws,
                  float* __restrict__ out) {
    // As_T[o=64][i'=192] bf16, XOR-swizzled: byte(o,i') = (o*384 + i'*2) ^ ((o&7)<<4)
    __shared__ __align__(16) unsigned short AsT[64 * 192];

    const int t    = threadIdx.x;
    const int wave = t >> 6, lane = t & 63;
    const int l15  = lane & 15, g = lane >> 4;
    const int bp   = blockIdx.x;
    const int b    = bp >> 10, p = bp & 1023;

    // zero pad rows o = 60..63 (read as B2 cols 60..63, never stored)
    #pragma unroll
    for (int r = 0; r < 3; r++) AsT[60 * 192 + r * 256 + t] = 0;

    // ================= GEMM-1: G[c][(ks,o)] = fs(64x60) * S(60x180) =================
    // waves: wm = wave&1 -> mtiles {2wm,2wm+1}; wn = wave>>1 -> ntiles [6wn, 6wn+6)
    const unsigned short* Sfrag = ws + 24576;
    const int wm = wave & 1, wn = wave >> 1;

    // hoist ALL S-fragments (12 x 16B, L2-resident) — issue back-to-back
    bf16x8 bfr[12];
    #pragma unroll
    for (int i = 0; i < 12; i++)
        bfr[i] = *(const bf16x8*)(Sfrag + ((wn * 12 + i) * 64 + lane) * 8);

    // A1 fragments from global feats (f32 -> bf16)
    bf16x8 a1[2][2];
    {
        const float* fb = feats + ((size_t)b * CIN * NPTS + p) * NA;
        #pragma unroll
        for (int mi = 0; mi < 2; mi++) {
            int c = (2 * wm + mi) * 16 + l15;
            const float* fr = fb + (size_t)c * NPTS * NA;
            #pragma unroll
            for (int kt = 0; kt < 2; kt++) {
                int a0 = kt * 32 + 8 * g;                 // a' base (multiple of 4)
                float4 lo = *(const float4*)(fr + a0);
                int ah = a0 + 4;
                float4 hi = *(const float4*)(fr + ((ah < NA) ? ah : 0)); // dead lanes: stay in-bounds
                bf16x8 v;
                v[0] = (short)f2bf(lo.x); v[1] = (short)f2bf(lo.y);
                v[2] = (short)f2bf(lo.z); v[3] = (short)f2bf(lo.w);
                v[4] = (short)f2bf(hi.x); v[5] = (short)f2bf(hi.y);
                v[6] = (short)f2bf(hi.z); v[7] = (short)f2bf(hi.w);
                a1[mi][kt] = v;
            }
        }
    }

    #pragma unroll
    for (int ni = 0; ni < 6; ni++) {
        int nt = wn * 6 + ni;
        int np = nt * 16 + l15;                    // n' = ks*60 + o
        int ks = (np >= 120) ? 2 : ((np >= 60) ? 1 : 0);
        int o  = np - 60 * ks;
        int sw = (o & 7) << 4;
        int rowbyte = o * 384;

        #pragma unroll
        for (int mi = 0; mi < 2; mi++) {
            f32x4 acc = {0.f, 0.f, 0.f, 0.f};
            acc = __builtin_amdgcn_mfma_f32_16x16x32_bf16(a1[mi][0], bfr[ni * 2 + 0], acc, 0, 0, 0);
            acc = __builtin_amdgcn_mfma_f32_16x16x32_bf16(a1[mi][1], bfr[ni * 2 + 1], acc, 0, 0, 0);
            if (np < 180) {
                // rows c = mt*16 + 4g + r, r=0..3 -> i' = ks*64 + c consecutive
                int cbase = (2 * wm + mi) * 16 + 4 * g;
                int ipb   = ks * 64 + cbase;
                unsigned int lo = (unsigned int)f2bf(acc[0]) | ((unsigned int)f2bf(acc[1]) << 16);
                unsigned int hi = (unsigned int)f2bf(acc[2]) | ((unsigned int)f2bf(acc[3]) << 16);
                int byte = (rowbyte + ipb * 2) ^ sw;   // 8B-aligned (cbase mult of 4)
                *(uint2*)((char*)AsT + byte) = make_uint2(lo, hi);
            }
        }
    }

    // ---- prefetch GEMM-2 A-fragments BEFORE the barrier: the barrier's
    // mandatory vmcnt(0) drain makes GEMM-1's tail cover their latency ----
    // wave owns mtiles {2*wave, 2*wave+1}, all 4 o-tiles
    bf16x8 a2[2][6];
    #pragma unroll
    for (int mi = 0; mi < 2; mi++)
        #pragma unroll
        for (int kt = 0; kt < 6; kt++)
            a2[mi][kt] = *(const bf16x8*)(ws + (((wave * 2 + mi) * 6 + kt) * 64 + lane) * 8);

    __syncthreads();

    // ================= GEMM-2: out[co][o] = W(128x192) * As(192x60) + bias =================
    int rb[4], swz[4], ov[4];
    #pragma unroll
    for (int nt = 0; nt < 4; nt++) {
        int o = nt * 16 + l15;
        ov[nt]  = o;
        rb[nt]  = o * 384;
        swz[nt] = (o & 7) << 4;
    }

    f32x4 acc[2][4];
    #pragma unroll
    for (int mi = 0; mi < 2; mi++)
        #pragma unroll
        for (int nt = 0; nt < 4; nt++) acc[mi][nt] = (f32x4){0.f, 0.f, 0.f, 0.f};

    #pragma unroll
    for (int kt = 0; kt < 6; kt++) {
        int x = (kt * 32 + 8 * g) * 2;             // 16B-aligned byte offset in row
        bf16x8 bb[4];
        #pragma unroll
        for (int nt = 0; nt < 4; nt++)
            bb[nt] = *(const bf16x8*)((char*)AsT + ((rb[nt] + x) ^ swz[nt]));
        #pragma unroll
        for (int mi = 0; mi < 2; mi++)
            #pragma unroll
            for (int nt = 0; nt < 4; nt++)
                acc[mi][nt] = __builtin_amdgcn_mfma_f32_16x16x32_bf16(a2[mi][kt], bb[nt], acc[mi][nt], 0, 0, 0);
    }

    // ---- epilogue: add bias, write out[b, co, p, o] ----
    #pragma unroll
    for (int mi = 0; mi < 2; mi++) {
        int cbase = (wave * 2 + mi) * 16 + 4 * g;
        float bv0 = bias[cbase + 0], bv1 = bias[cbase + 1];
        float bv2 = bias[cbase + 2], bv3 = bias[cbase + 3];
        float* ob = out + (((size_t)b * COUT + cbase) * NPTS + p) * NA;
        const size_t cs = (size_t)NPTS * NA;
        #pragma unroll
        for (int nt = 0; nt < 4; nt++) {
            if (ov[nt] < NA) {
                ob[0 * cs + ov[nt]] = acc[mi][nt][0] + bv0;
                ob[1 * cs + ov[nt]] = acc[mi][nt][1] + bv1;
                ob[2 * cs + ov[nt]] = acc[mi][nt][2] + bv2;
                ob[3 * cs + ov[nt]] = acc[mi][nt][3] + bv3;
            }
        }
    }
}

extern "C" void kernel_launch(void* const* d_in, const int* in_sizes, int n_in,
                              void* d_out, int out_size, void* d_ws, size_t ws_size,
                              hipStream_t stream) {
    const float* feats     = (const float*)d_in[0];
    const float* intra_w   = (const float*)d_in[1];
    const float* W         = (const float*)d_in[2];
    const float* bias      = (const float*)d_in[3];
    const int*   intra_idx = (const int*)d_in[4];
    float* out = (float*)d_out;
    unsigned short* ws = (unsigned short*)d_ws;   // needs 73728 B

    build_tables<<<dim3(144), dim3(256), 0, stream>>>(intra_w, W, intra_idx, ws);
    intrazp_mfma<<<dim3(2 * NPTS), dim3(256), 0, stream>>>(feats, bias, ws, out);
}

// Round 4
// 117.887 us; speedup vs baseline: 1.0354x; 1.0354x over previous
//
#include <hip/hip_runtime.h>

#define NPTS 1024
#define NA   60
#define CIN  64
#define KSZ  3
#define ANN  8
#define COUT 128
#define KD   192   // i' = k_s*64 + c, 6 k-tiles of 32

using bf16x8 = __attribute__((ext_vector_type(8))) short;
using f32x4  = __attribute__((ext_vector_type(4))) float;

__device__ __forceinline__ unsigned short f2bf(float f) {
    unsigned int u = __builtin_bit_cast(unsigned int, f);
    u += 0x7FFFu + ((u >> 16) & 1u);          // RNE
    return (unsigned short)(u >> 16);
}

// ---------------- pre-kernel: build W_frag + S_frag in d_ws ----------------
// ws[0 .. 24576)        : W_frag[mt=8][kt=6][lane=64][j=8]  bf16, A-frag layout
// ws[24576 .. 36864)    : S_frag[nt=12][kt=2][lane=64][j=8] bf16, B-frag layout
__global__ void build_tables(const float* __restrict__ intra_w,
                             const float* __restrict__ W,
                             const int*   __restrict__ intra_idx,
                             unsigned short* __restrict__ ws) {
    int f = blockIdx.x * 256 + threadIdx.x;
    if (f < 24576) {
        int j = f & 7, l = (f >> 3) & 63, x = f >> 9;
        int kt = x % 6, mt = x / 6;
        int m  = mt * 16 + (l & 15);
        int ip = kt * 32 + 8 * (l >> 4) + j;      // i'
        int c  = ip & 63, ks = ip >> 6;
        ws[f] = f2bf(W[m * KD + c * KSZ + ks]);
    } else if (f < 36864) {
        int f2 = f - 24576;
        int j = f2 & 7, l = (f2 >> 3) & 63;
        int kt = (f2 >> 9) & 1, nt = f2 >> 10;
        int np = nt * 16 + (l & 15);              // n' = ks*60+o
        int ap = kt * 32 + 8 * (l >> 4) + j;      // a'
        float s = 0.f;
        if (np < 180 && ap < 60) {
            int ks = (np >= 120) ? 2 : ((np >= 60) ? 1 : 0);
            int o  = np - 60 * ks;
            const int*   ix = intra_idx + (o * KSZ + ks) * ANN;
            const float* wx = intra_w   + (o * KSZ + ks) * ANN;
            #pragma unroll
            for (int a = 0; a < ANN; a++) s += (ix[a] == ap) ? wx[a] : 0.f;
        }
        ws[f] = f2bf(s);
    }
}

// ---------------- main kernel: one block per (b,p), 256 threads ----------------
__global__ __launch_bounds__(256, 4)
void intrazp_mfma(const float* __restrict__ feats,
                  const float* __restrict__ bias,
                  const unsigned short* __restrict__ ws,
                  float* __restrict__ out) {
    // fsS[c=64][a=64] bf16, swizzled:  byte(c,a) = (c*128 + a*2) ^ ((c&7)<<4)
    // AsT[o=64][i'=192] bf16, swizzled: byte(o,i') = (o*384 + i'*2) ^ ((o&7)<<4)
    __shared__ __align__(16) unsigned short fsS[64 * 64];
    __shared__ __align__(16) unsigned short AsT[64 * 192];

    const int t    = threadIdx.x;
    const int wave = t >> 6, lane = t & 63;
    const int l15  = lane & 15, g = lane >> 4;
    // bijective XCD swizzle: 2048 = 8 XCDs x 256 contiguous (b,p) chunks
    const int bid = blockIdx.x;
    const int bp  = (bid & 7) * 256 + (bid >> 3);
    const int b   = bp >> 10, p = bp & 1023;

    // ---- phase 0: coalesced staging of feats[b,:,p,:] into fsS (bf16) ----
    {
        const float* fb = feats + (size_t)b * CIN * NPTS * NA + (size_t)p * NA;
        #pragma unroll
        for (int r = 0; r < 4; r++) {
            int q = t + r * 256;                  // chunk id, 15 float4 per c-row
            if (q < 960) {
                int c = q / 15, w = q - c * 15;
                float4 v = *(const float4*)(fb + (size_t)c * NPTS * NA + w * 4);
                unsigned int lo = (unsigned int)f2bf(v.x) | ((unsigned int)f2bf(v.y) << 16);
                unsigned int hi = (unsigned int)f2bf(v.z) | ((unsigned int)f2bf(v.w) << 16);
                int byte = (c * 128 + w * 8) ^ ((c & 7) << 4);
                *(uint2*)((char*)fsS + byte) = make_uint2(lo, hi);
            }
        }
        if (t < 64) {   // zero-pad a = 60..63
            int byte = (t * 128 + 120) ^ ((t & 7) << 4);
            *(uint2*)((char*)fsS + byte) = make_uint2(0u, 0u);
        }
        if (t < 192) {  // zero-pad AsT rows o = 60..63 (1536 B)
            *(uint2*)((char*)AsT + 60 * 384 + t * 8) = make_uint2(0u, 0u);
        }
    }
    __syncthreads();

    // ================= GEMM-1: G[c][(ks,o)] = fs(64x60) * S(60x180) =================
    const unsigned short* Sfrag = ws + 24576;
    const int wm = wave & 1, wn = wave >> 1;

    // A1 fragments from LDS (conflict-free-ish via swizzle)
    bf16x8 a1[2][2];
    #pragma unroll
    for (int mi = 0; mi < 2; mi++) {
        int c = (2 * wm + mi) * 16 + l15;
        #pragma unroll
        for (int kt = 0; kt < 2; kt++) {
            int byte = (c * 128 + kt * 64 + g * 16) ^ ((c & 7) << 4);
            a1[mi][kt] = *(const bf16x8*)((char*)fsS + byte);
        }
    }

    #pragma unroll
    for (int ni = 0; ni < 6; ni++) {
        int nt = wn * 6 + ni;
        bf16x8 b0 = *(const bf16x8*)(Sfrag + ((nt * 2 + 0) * 64 + lane) * 8);
        bf16x8 b1 = *(const bf16x8*)(Sfrag + ((nt * 2 + 1) * 64 + lane) * 8);

        int np = nt * 16 + l15;                    // n' = ks*60 + o
        int ks = (np >= 120) ? 2 : ((np >= 60) ? 1 : 0);
        int o  = np - 60 * ks;
        int sw = (o & 7) << 4;
        int rowbyte = o * 384;

        #pragma unroll
        for (int mi = 0; mi < 2; mi++) {
            f32x4 acc = {0.f, 0.f, 0.f, 0.f};
            acc = __builtin_amdgcn_mfma_f32_16x16x32_bf16(a1[mi][0], b0, acc, 0, 0, 0);
            acc = __builtin_amdgcn_mfma_f32_16x16x32_bf16(a1[mi][1], b1, acc, 0, 0, 0);
            if (np < 180) {
                int cbase = (2 * wm + mi) * 16 + 4 * g;
                int ipb   = ks * 64 + cbase;       // i' rows consecutive
                unsigned int lo = (unsigned int)f2bf(acc[0]) | ((unsigned int)f2bf(acc[1]) << 16);
                unsigned int hi = (unsigned int)f2bf(acc[2]) | ((unsigned int)f2bf(acc[3]) << 16);
                int byte = (rowbyte + ipb * 2) ^ sw;
                *(uint2*)((char*)AsT + byte) = make_uint2(lo, hi);
            }
        }
    }

    // prefetch GEMM-2 A-fragments before the barrier (L2-resident W_frag)
    bf16x8 a2[2][6];
    #pragma unroll
    for (int mi = 0; mi < 2; mi++)
        #pragma unroll
        for (int kt = 0; kt < 6; kt++)
            a2[mi][kt] = *(const bf16x8*)(ws + (((wave * 2 + mi) * 6 + kt) * 64 + lane) * 8);

    __syncthreads();

    // ================= GEMM-2: out[co][o] = W(128x192) * As(192x60) + bias =================
    int rb[4], swz[4], ov[4];
    #pragma unroll
    for (int nt = 0; nt < 4; nt++) {
        int o = nt * 16 + l15;
        ov[nt]  = o;
        rb[nt]  = o * 384;
        swz[nt] = (o & 7) << 4;
    }

    f32x4 acc[2][4];
    #pragma unroll
    for (int mi = 0; mi < 2; mi++)
        #pragma unroll
        for (int nt = 0; nt < 4; nt++) acc[mi][nt] = (f32x4){0.f, 0.f, 0.f, 0.f};

    #pragma unroll
    for (int kt = 0; kt < 6; kt++) {
        int x = (kt * 32 + 8 * g) * 2;
        bf16x8 bb[4];
        #pragma unroll
        for (int nt = 0; nt < 4; nt++)
            bb[nt] = *(const bf16x8*)((char*)AsT + ((rb[nt] + x) ^ swz[nt]));
        #pragma unroll
        for (int mi = 0; mi < 2; mi++)
            #pragma unroll
            for (int nt = 0; nt < 4; nt++)
                acc[mi][nt] = __builtin_amdgcn_mfma_f32_16x16x32_bf16(a2[mi][kt], bb[nt], acc[mi][nt], 0, 0, 0);
    }

    // ---- epilogue: add bias, write out[b, co, p, o] ----
    #pragma unroll
    for (int mi = 0; mi < 2; mi++) {
        int cbase = (wave * 2 + mi) * 16 + 4 * g;
        float bv0 = bias[cbase + 0], bv1 = bias[cbase + 1];
        float bv2 = bias[cbase + 2], bv3 = bias[cbase + 3];
        float* ob = out + (((size_t)b * COUT + cbase) * NPTS + p) * NA;
        const size_t cs = (size_t)NPTS * NA;
        #pragma unroll
        for (int nt = 0; nt < 4; nt++) {
            if (ov[nt] < NA) {
                ob[0 * cs + ov[nt]] = acc[mi][nt][0] + bv0;
                ob[1 * cs + ov[nt]] = acc[mi][nt][1] + bv1;
                ob[2 * cs + ov[nt]] = acc[mi][nt][2] + bv2;
                ob[3 * cs + ov[nt]] = acc[mi][nt][3] + bv3;
            }
        }
    }
}

extern "C" void kernel_launch(void* const* d_in, const int* in_sizes, int n_in,
                              void* d_out, int out_size, void* d_ws, size_t ws_size,
                              hipStream_t stream) {
    const float* feats     = (const float*)d_in[0];
    const float* intra_w   = (const float*)d_in[1];
    const float* W         = (const float*)d_in[2];
    const float* bias      = (const float*)d_in[3];
    const int*   intra_idx = (const int*)d_in[4];
    float* out = (float*)d_out;
    unsigned short* ws = (unsigned short*)d_ws;   // needs 73728 B

    build_tables<<<dim3(144), dim3(256), 0, stream>>>(intra_w, W, intra_idx, ws);
    intrazp_mfma<<<dim3(2 * NPTS), dim3(256), 0, stream>>>(feats, bias, ws, out);
}